// Round 1
// baseline (1461.863 us; speedup 1.0000x reference)
//
#include <hip/hip_runtime.h>
#include <hip/hip_bf16.h>

// Pipeline:
//  deg[s] += (s!=d)            (atomic, over E)
//  dinv = deg>0 ? rsqrt(deg):0
//  a3 = x@W0a, y3 = x@W1a      ([N,64]->[N,3] each)
//  t1[d] += -dinv[s]*dinv[d]*y3[s]   (3-wide scatter)
//  h1 = relu(a3 + t1 + b1)
//  t2[d] += -dinv[s]*dinv[d]*h1[s]
//  h2 = relu(h1@W0b + t2@W1b + b2)   (256 wide, fused into final)
//  out = h2@Wl + bl                  ([N,256]x[256,512])

__global__ void k_deg(const int* __restrict__ ei, float* __restrict__ deg, int E) {
    int e = blockIdx.x * blockDim.x + threadIdx.x;
    if (e >= E) return;
    int s = ei[e], d = ei[E + e];
    if (s != d) atomicAdd(&deg[s], 1.0f);
}

__global__ void k_dinv(const float* __restrict__ deg, float* __restrict__ dinv, int n) {
    int i = blockIdx.x * blockDim.x + threadIdx.x;
    if (i >= n) return;
    float dg = deg[i];
    dinv[i] = dg > 0.f ? rsqrtf(dg) : 0.f;
}

// x[N,64] @ (W0a[64,3] | W1a[64,3]) -> a3[N,3], y3[N,3]
__global__ void k_gemm1(const float* __restrict__ x, const float* __restrict__ W0a,
                        const float* __restrict__ W1a, float* __restrict__ a3,
                        float* __restrict__ y3, int n) {
    __shared__ float w0[192], w1[192];
    int t = threadIdx.x;
    if (t < 192) { w0[t] = W0a[t]; w1[t] = W1a[t]; }
    __syncthreads();
    int node = blockIdx.x * blockDim.x + t;
    if (node >= n) return;
    const float4* xr = (const float4*)(x + (size_t)node * 64);
    float a0 = 0.f, a1 = 0.f, a2 = 0.f, c0 = 0.f, c1 = 0.f, c2 = 0.f;
#pragma unroll
    for (int i = 0; i < 16; i++) {
        float4 v = xr[i];
        float xs[4] = {v.x, v.y, v.z, v.w};
#pragma unroll
        for (int c = 0; c < 4; c++) {
            int f = i * 4 + c;
            float xi = xs[c];
            a0 += xi * w0[f * 3 + 0];
            a1 += xi * w0[f * 3 + 1];
            a2 += xi * w0[f * 3 + 2];
            c0 += xi * w1[f * 3 + 0];
            c1 += xi * w1[f * 3 + 1];
            c2 += xi * w1[f * 3 + 2];
        }
    }
    a3[node * 3 + 0] = a0; a3[node * 3 + 1] = a1; a3[node * 3 + 2] = a2;
    y3[node * 3 + 0] = c0; y3[node * 3 + 1] = c1; y3[node * 3 + 2] = c2;
}

// o3[d] += -dinv[s]*dinv[d] * v3[s]   (3 floats per edge)
__global__ void k_scatter3(const int* __restrict__ ei, const float* __restrict__ dinv,
                           const float* __restrict__ v3, float* __restrict__ o3, int E) {
    int e = blockIdx.x * blockDim.x + threadIdx.x;
    if (e >= E) return;
    int s = ei[e], d = ei[E + e];
    if (s == d) return;
    float nm = -dinv[s] * dinv[d];
    if (nm == 0.f) return;
    atomicAdd(&o3[d * 3 + 0], nm * v3[s * 3 + 0]);
    atomicAdd(&o3[d * 3 + 1], nm * v3[s * 3 + 1]);
    atomicAdd(&o3[d * 3 + 2], nm * v3[s * 3 + 2]);
}

__global__ void k_h1(const float* __restrict__ a3, const float* __restrict__ t1,
                     const float* __restrict__ b1, float* __restrict__ h1, int n3) {
    int i = blockIdx.x * blockDim.x + threadIdx.x;
    if (i >= n3) return;
    float v = a3[i] + t1[i] + b1[i % 3];
    h1[i] = fmaxf(v, 0.f);
}

// Per block: 32 nodes. Phase 1: h2T[k][n] = relu(z) staged in LDS (k-major).
// Phase 2: each thread owns output cols (t, t+256), k-loop with LDS broadcast.
__global__ __launch_bounds__(256) void k_final(
    const float* __restrict__ h1, const float* __restrict__ t2,
    const float* __restrict__ W0b, const float* __restrict__ W1b,
    const float* __restrict__ b2, const float* __restrict__ Wl,
    const float* __restrict__ bl, float* __restrict__ out, int n) {
    __shared__ float h2T[256][32];  // 32 KB, k-major for b128 broadcast reads
    __shared__ float u6[32][6];     // [h1(3) | t2(3)] per node
    int t = threadIdx.x;
    int n0 = blockIdx.x * 32;
    if (t < 96) {
        int nn = t / 3, k = t % 3;
        int g = n0 + nn;
        float hv = 0.f, tv = 0.f;
        if (g < n) { hv = h1[g * 3 + k]; tv = t2[g * 3 + k]; }
        u6[nn][k] = hv;
        u6[nn][3 + k] = tv;
    }
    __syncthreads();
    {
        float w00 = W0b[t], w01 = W0b[256 + t], w02 = W0b[512 + t];
        float w10 = W1b[t], w11 = W1b[256 + t], w12 = W1b[512 + t];
        float bk = b2[t];
#pragma unroll
        for (int nn = 0; nn < 32; nn++) {
            float z = bk + u6[nn][0] * w00 + u6[nn][1] * w01 + u6[nn][2] * w02
                         + u6[nn][3] * w10 + u6[nn][4] * w11 + u6[nn][5] * w12;
            h2T[t][nn] = fmaxf(z, 0.f);
        }
    }
    __syncthreads();
    float acc0[32], acc1[32];
#pragma unroll
    for (int nn = 0; nn < 32; nn++) { acc0[nn] = 0.f; acc1[nn] = 0.f; }
    const float* wlc = Wl + t;
#pragma unroll 2
    for (int k = 0; k < 256; k++) {
        float wl0 = wlc[(size_t)k * 512];
        float wl1 = wlc[(size_t)k * 512 + 256];
#pragma unroll
        for (int nn = 0; nn < 32; nn++) {
            float h = h2T[k][nn];
            acc0[nn] += h * wl0;
            acc1[nn] += h * wl1;
        }
    }
    float bl0 = bl[t], bl1 = bl[t + 256];
#pragma unroll
    for (int nn = 0; nn < 32; nn++) {
        int g = n0 + nn;
        if (g < n) {
            out[(size_t)g * 512 + t] = acc0[nn] + bl0;
            out[(size_t)g * 512 + 256 + t] = acc1[nn] + bl1;
        }
    }
}

extern "C" void kernel_launch(void* const* d_in, const int* in_sizes, int n_in,
                              void* d_out, int out_size, void* d_ws, size_t ws_size,
                              hipStream_t stream) {
    const float* x   = (const float*)d_in[0];
    const int*   ei  = (const int*)d_in[1];
    const float* W0a = (const float*)d_in[2];
    const float* W1a = (const float*)d_in[3];
    const float* b1  = (const float*)d_in[4];
    const float* W0b = (const float*)d_in[5];
    const float* W1b = (const float*)d_in[6];
    const float* b2  = (const float*)d_in[7];
    const float* Wl  = (const float*)d_in[8];
    const float* bl  = (const float*)d_in[9];
    float* out = (float*)d_out;

    const int N = in_sizes[0] / 64;
    const int E = in_sizes[1] / 2;

    float* ws   = (float*)d_ws;
    float* deg  = ws;             // N
    float* t1   = ws + N;         // 3N
    float* t2   = ws + 4 * N;     // 3N
    float* dinv = ws + 7 * N;     // N
    float* a3   = ws + 8 * N;     // 3N
    float* y3   = ws + 11 * N;    // 3N
    float* h1   = ws + 14 * N;    // 3N  (total 17N floats = 6.8 MB)

    hipMemsetAsync(ws, 0, (size_t)7 * N * sizeof(float), stream);  // deg, t1, t2

    k_deg<<<(E + 255) / 256, 256, 0, stream>>>(ei, deg, E);
    k_dinv<<<(N + 255) / 256, 256, 0, stream>>>(deg, dinv, N);
    k_gemm1<<<(N + 255) / 256, 256, 0, stream>>>(x, W0a, W1a, a3, y3, N);
    k_scatter3<<<(E + 255) / 256, 256, 0, stream>>>(ei, dinv, y3, t1, E);
    k_h1<<<(3 * N + 255) / 256, 256, 0, stream>>>(a3, t1, b1, h1, 3 * N);
    k_scatter3<<<(E + 255) / 256, 256, 0, stream>>>(ei, dinv, h1, t2, E);
    k_final<<<(N + 31) / 32, 256, 0, stream>>>(h1, t2, W0b, W1b, b2, Wl, bl, out, N);
}